// Round 5
// baseline (534.715 us; speedup 1.0000x reference)
//
#include <hip/hip_runtime.h>
#include <math.h>

#define NH 12
#define HD 64
#define SEQ 1024
#define BATCH 8
#define HDIM 768
#define FFDIM 3072
#define MTOT (BATCH*SEQ)   // 8192

typedef __attribute__((ext_vector_type(8))) short short8;
typedef __attribute__((ext_vector_type(4))) float f32x4;
typedef __attribute__((ext_vector_type(4))) unsigned short ushort4v;

__device__ __forceinline__ unsigned short f2b(float f) {
    union { float f; unsigned u; } v; v.f = f;
    unsigned r = v.u + 0x7fffu + ((v.u >> 16) & 1u);  // RNE
    return (unsigned short)(r >> 16);
}

__device__ __forceinline__ f32x4 mfma16(short8 a, short8 b, f32x4 c) {
    return __builtin_amdgcn_mfma_f32_16x16x32_bf16(a, b, c, 0, 0, 0);
}

// async global->LDS, 16B per lane. HW writes lds_base + lane*16; lds ptr must be wave-uniform.
__device__ __forceinline__ void async_copy16(const unsigned short* g, unsigned short* l) {
    __builtin_amdgcn_global_load_lds(
        (const __attribute__((address_space(1))) unsigned int*)(const void*)g,
        (__attribute__((address_space(3))) unsigned int*)(void*)l, 16, 0, 0);
}

// XCD-aware M-tile remap: consecutive bids round-robin XCDs; with GX%8==0 this
// gives XCD k a contiguous gx chunk, so each XCD's L2 keeps its own A-panel slice.
__device__ __forceinline__ int xcd_remap_x(int gx, int GX) {
    return ((GX & 7) == 0) ? (gx & 7) * (GX >> 3) + (gx >> 3) : gx;
}

// ---------------- convert f32 -> bf16 ----------------
__global__ __launch_bounds__(256) void k_cvt(const float* __restrict__ in,
                                             unsigned short* __restrict__ out, int n) {
    int idx = (blockIdx.x * 256 + threadIdx.x) * 4;
    if (idx >= n) return;
    float4 v = *reinterpret_cast<const float4*>(in + idx);
    ushort4v o;
    o[0] = f2b(v.x); o[1] = f2b(v.y); o[2] = f2b(v.z); o[3] = f2b(v.w);
    *reinterpret_cast<ushort4v*>(out + idx) = o;
}

// ---------------- transpose + convert: W[K][N] f32 -> WT[N][K] bf16 ----------------
__global__ __launch_bounds__(256) void k_wt4(const float* __restrict__ W0,
                                             const float* __restrict__ W1,
                                             const float* __restrict__ W2,
                                             const float* __restrict__ W3,
                                             unsigned short* __restrict__ WT) {
    __shared__ float t[32][33];
    const float* W = (blockIdx.z == 0) ? W0 : (blockIdx.z == 1) ? W1 :
                     (blockIdx.z == 2) ? W2 : W3;
    unsigned short* dst = WT + (size_t)blockIdx.z * 768 * 768;
    int n0 = blockIdx.x * 32, k0 = blockIdx.y * 32;
    int x = threadIdx.x & 31, y = threadIdx.x >> 5;
#pragma unroll
    for (int i = y; i < 32; i += 8) t[i][x] = W[(size_t)(k0 + i) * 768 + n0 + x];
    __syncthreads();
#pragma unroll
    for (int i = y; i < 32; i += 8) dst[(size_t)(n0 + i) * 768 + k0 + x] = f2b(t[x][i]);
}

__global__ __launch_bounds__(256) void k_wt(const float* __restrict__ W,
                                            unsigned short* __restrict__ WT, int K, int Nn) {
    __shared__ float t[32][33];
    int n0 = blockIdx.x * 32, k0 = blockIdx.y * 32;
    int x = threadIdx.x & 31, y = threadIdx.x >> 5;
#pragma unroll
    for (int i = y; i < 32; i += 8) t[i][x] = W[(size_t)(k0 + i) * Nn + n0 + x];
    __syncthreads();
#pragma unroll
    for (int i = y; i < 32; i += 8) WT[(size_t)(n0 + i) * K + k0 + x] = f2b(t[x][i]);
}

// ---------------- concat qkv bias ----------------
__global__ void k_bias3(const float* __restrict__ a, const float* __restrict__ b,
                        const float* __restrict__ c, float* __restrict__ o) {
    int i = blockIdx.x * 256 + threadIdx.x;
    if (i >= 3 * HDIM) return;
    o[i] = (i < HDIM) ? a[i] : (i < 2 * HDIM ? b[i - HDIM] : c[i - 2 * HDIM]);
}

// ---------------- epilogue helper ----------------
template<int EPI>
__device__ __forceinline__ void epi_store(float v, size_t oi,
                                          unsigned short* outb, float* outf,
                                          const float* resid) {
    if constexpr (EPI == 0) {
        outb[oi] = f2b(v);
    } else if constexpr (EPI == 1) {
        outf[oi] = v + resid[oi];
    } else {
        float g = 0.5f * v * (1.0f + erff(v * 0.70710678118654752f));
        outb[oi] = f2b(g);
    }
}

// ---------------- 4-wave 128x128 GEMM (verified round-4 path) ----------------
// C[M][N] = A[M][K] * BT[N][K]^T, BK=64, gload_lds into XOR-swizzled LDS.
template<int EPI>
__global__ __launch_bounds__(256) void k_gemm(const unsigned short* __restrict__ A,
                                              const unsigned short* __restrict__ BT,
                                              const float* __restrict__ bias,
                                              const float* __restrict__ resid,
                                              unsigned short* __restrict__ outb,
                                              float* __restrict__ outf,
                                              int Ndim, int Kdim) {
    __shared__ unsigned short As[128 * 64];
    __shared__ unsigned short Bs[128 * 64];
    int tid = threadIdx.x;
    int wid = tid >> 6, lane = tid & 63;
    int wm = wid >> 1, wn = wid & 1;
    int l15 = lane & 15, l16 = lane >> 4;
    int gx = xcd_remap_x(blockIdx.x, gridDim.x);
    int bm = gx * 128, bn = blockIdx.y * 128;

    int srow = wid * 8 + (lane >> 3);
    int scol = 8 * ((lane & 7) ^ (lane >> 3));
    const unsigned short* aptr = A + (size_t)(bm + srow) * Kdim + scol;
    const unsigned short* bptr = BT + (size_t)(bn + srow) * Kdim + scol;

    f32x4 acc[4][4] = {};
    const int swz = (l15 & 7) << 3;

    for (int kt = 0; kt < Kdim; kt += 64) {
#pragma unroll
        for (int c = 0; c < 4; c++) {
            async_copy16(aptr + (size_t)c * 32 * Kdim + kt, As + c * 2048 + wid * 512);
            async_copy16(bptr + (size_t)c * 32 * Kdim + kt, Bs + c * 2048 + wid * 512);
        }
        __syncthreads();
#pragma unroll
        for (int kk = 0; kk < 2; kk++) {
            short8 af[4], bfr[4];
            int cidx = (kk * 32 + l16 * 8) ^ swz;
#pragma unroll
            for (int i = 0; i < 4; i++) {
                af[i]  = *reinterpret_cast<const short8*>(&As[(wm * 64 + i * 16 + l15) * 64 + cidx]);
                bfr[i] = *reinterpret_cast<const short8*>(&Bs[(wn * 64 + i * 16 + l15) * 64 + cidx]);
            }
#pragma unroll
            for (int i = 0; i < 4; i++)
#pragma unroll
                for (int j = 0; j < 4; j++)
                    acc[i][j] = mfma16(af[i], bfr[j], acc[i][j]);
        }
        __syncthreads();
    }

#pragma unroll
    for (int i = 0; i < 4; i++)
#pragma unroll
        for (int j = 0; j < 4; j++) {
            int grow0 = bm + wm * 64 + i * 16 + l16 * 4;
            int gcol = bn + wn * 64 + j * 16 + l15;
            float bcol = bias[gcol];
#pragma unroll
            for (int r = 0; r < 4; r++)
                epi_store<EPI>(acc[i][j][r] + bcol, (size_t)(grow0 + r) * Ndim + gcol,
                               outb, outf, resid);
        }
}

// ---------------- 8-wave GEMM: BM = MT*32 (MT=8 -> 256x256, MT=4 -> 128x256) ----------------
// waves 2x4: wave tile (MT*16) x 64. Same BK=64 swizzled staging.
template<int MT, int EPI>
__global__ __launch_bounds__(512, 2) void k_gemm8(const unsigned short* __restrict__ A,
                                                  const unsigned short* __restrict__ BT,
                                                  const float* __restrict__ bias,
                                                  const float* __restrict__ resid,
                                                  unsigned short* __restrict__ outb,
                                                  float* __restrict__ outf,
                                                  int Ndim, int Kdim) {
    constexpr int BM = MT * 32;
    __shared__ unsigned short As[BM * 64];
    __shared__ unsigned short Bs[256 * 64];
    int tid = threadIdx.x;
    int wid = tid >> 6, lane = tid & 63;
    int wm = wid >> 2, wn = wid & 3;
    int l15 = lane & 15, l16 = lane >> 4;
    int gx = xcd_remap_x(blockIdx.x, gridDim.x);
    int bm = gx * BM, bn = blockIdx.y * 256;

    // staging round c: rows [c*64, c*64+64); thread byte = c*8192 + tid*16
    int srow = (tid >> 3) & 7;              // (wid*8 + lane>>3) low 3 bits == lane>>3
    int srow_full = wid * 8 + (lane >> 3);  // 0..63 within a round
    int scol = 8 * ((lane & 7) ^ (lane >> 3));
    const unsigned short* aptr = A + (size_t)(bm + srow_full) * Kdim + scol;
    const unsigned short* bptr = BT + (size_t)(bn + srow_full) * Kdim + scol;
    (void)srow;

    f32x4 acc[MT][4] = {};
    const int swz = (l15 & 7) << 3;

    for (int kt = 0; kt < Kdim; kt += 64) {
#pragma unroll
        for (int c = 0; c < BM / 64; c++)
            async_copy16(aptr + (size_t)c * 64 * Kdim + kt, As + c * 4096 + wid * 512);
#pragma unroll
        for (int c = 0; c < 4; c++)
            async_copy16(bptr + (size_t)c * 64 * Kdim + kt, Bs + c * 4096 + wid * 512);
        __syncthreads();
#pragma unroll
        for (int kk = 0; kk < 2; kk++) {
            short8 af[MT], bfr[4];
            int cidx = (kk * 32 + l16 * 8) ^ swz;
#pragma unroll
            for (int i = 0; i < MT; i++)
                af[i] = *reinterpret_cast<const short8*>(
                    &As[(wm * (MT * 16) + i * 16 + l15) * 64 + cidx]);
#pragma unroll
            for (int j = 0; j < 4; j++)
                bfr[j] = *reinterpret_cast<const short8*>(
                    &Bs[(wn * 64 + j * 16 + l15) * 64 + cidx]);
#pragma unroll
            for (int i = 0; i < MT; i++)
#pragma unroll
                for (int j = 0; j < 4; j++)
                    acc[i][j] = mfma16(af[i], bfr[j], acc[i][j]);
        }
        __syncthreads();
    }

#pragma unroll
    for (int i = 0; i < MT; i++)
#pragma unroll
        for (int j = 0; j < 4; j++) {
            int grow0 = bm + wm * (MT * 16) + i * 16 + l16 * 4;
            int gcol = bn + wn * 64 + j * 16 + l15;
            float bcol = bias[gcol];
#pragma unroll
            for (int r = 0; r < 4; r++)
                epi_store<EPI>(acc[i][j][r] + bcol, (size_t)(grow0 + r) * Ndim + gcol,
                               outb, outf, resid);
        }
}

// ---------------- flash attention with additive bias (measured-good) ----------------
__global__ __launch_bounds__(256) void k_attn(const unsigned short* __restrict__ QKV,
                                              const float* __restrict__ bias,
                                              unsigned short* __restrict__ out) {
    __shared__ unsigned short Ks[64][72];
    __shared__ unsigned short Vt[64][72];   // Vt[d][kn ^ swz(d)] = V[kn][d]
    __shared__ unsigned short Ps[4][16][72];

    int bh = blockIdx.y;
    int b = bh / NH, h = bh % NH;
    int q0 = blockIdx.x * 64;
    int tid = threadIdx.x, wid = tid >> 6, lane = tid & 63;
    int l15 = lane & 15, l16 = lane >> 4;

    size_t qrow = (size_t)(b * SEQ + q0 + wid * 16 + l15) * 2304 + h * 64;
    short8 qf0 = *reinterpret_cast<const short8*>(&QKV[qrow + l16 * 8]);
    short8 qf1 = *reinterpret_cast<const short8*>(&QKV[qrow + 32 + l16 * 8]);

    f32x4 o[4] = {};
    float mrow[4], lrow[4];
#pragma unroll
    for (int r = 0; r < 4; r++) { mrow[r] = -1e30f; lrow[r] = 0.0f; }

    for (int kt = 0; kt < SEQ; kt += 64) {
#pragma unroll
        for (int it = 0; it < 2; ++it) {
            int idx = tid + it * 256;           // 0..511
            int r = idx >> 3, c8 = (idx & 7) * 8;
            size_t gr = (size_t)(b * SEQ + kt + r) * 2304 + h * 64;
            *reinterpret_cast<short8*>(&Ks[r][c8]) =
                *reinterpret_cast<const short8*>(&QKV[gr + 768 + c8]);
            short8 vv = *reinterpret_cast<const short8*>(&QKV[gr + 1536 + c8]);
            int cc = r ^ c8;
#pragma unroll
            for (int j = 0; j < 8; j++) Vt[c8 + j][cc] = (unsigned short)vv[j];
        }
        __syncthreads();

        f32x4 s[4];
#pragma unroll
        for (int c = 0; c < 4; c++) {
            f32x4 t = {};
            t = mfma16(qf0, *reinterpret_cast<const short8*>(&Ks[c * 16 + l15][l16 * 8]), t);
            t = mfma16(qf1, *reinterpret_cast<const short8*>(&Ks[c * 16 + l15][32 + l16 * 8]), t);
            s[c] = t;
        }
#pragma unroll
        for (int c = 0; c < 4; c++)
#pragma unroll
            for (int r = 0; r < 4; r++) {
                size_t bi = (size_t)h * SEQ * SEQ +
                            (size_t)(q0 + wid * 16 + l16 * 4 + r) * SEQ + kt + c * 16 + l15;
                s[c][r] = s[c][r] * 0.125f + bias[bi];
            }
#pragma unroll
        for (int r = 0; r < 4; r++) {
            float mx = fmaxf(fmaxf(s[0][r], s[1][r]), fmaxf(s[2][r], s[3][r]));
#pragma unroll
            for (int off = 1; off < 16; off <<= 1) mx = fmaxf(mx, __shfl_xor(mx, off, 64));
            float mnew = fmaxf(mrow[r], mx);
            float resc = __expf(mrow[r] - mnew);
            mrow[r] = mnew;
            float sum = 0.0f;
#pragma unroll
            for (int c = 0; c < 4; c++) {
                float p = __expf(s[c][r] - mnew);
                s[c][r] = p; sum += p;
            }
#pragma unroll
            for (int off = 1; off < 16; off <<= 1) sum += __shfl_xor(sum, off, 64);
            lrow[r] = lrow[r] * resc + sum;
#pragma unroll
            for (int dc = 0; dc < 4; dc++) o[dc][r] *= resc;
        }
#pragma unroll
        for (int c = 0; c < 4; c++)
#pragma unroll
            for (int r = 0; r < 4; r++)
                Ps[wid][l16 * 4 + r][c * 16 + l15] = f2b(s[c][r]);
#pragma unroll
        for (int dc = 0; dc < 4; dc++) {
            int d = dc * 16 + l15;
            int sw = ((d >> 3) & 7) << 3;
#pragma unroll
            for (int kk = 0; kk < 2; kk++) {
                short8 pa = *reinterpret_cast<const short8*>(&Ps[wid][l15][kk * 32 + l16 * 8]);
                short8 vb = *reinterpret_cast<const short8*>(&Vt[d][(kk * 32 + l16 * 8) ^ sw]);
                o[dc] = mfma16(pa, vb, o[dc]);
            }
        }
        __syncthreads();
    }

#pragma unroll
    for (int dc = 0; dc < 4; dc++)
#pragma unroll
        for (int r = 0; r < 4; r++) {
            float v = o[dc][r] / lrow[r];
            size_t row = (size_t)(b * SEQ + q0 + wid * 16 + l16 * 4 + r);
            out[row * 768 + h * 64 + dc * 16 + l15] = f2b(v);
        }
}

// ---------------- LayerNorm over 768 cols ----------------
template<int WB>
__global__ __launch_bounds__(256) void k_ln(const float* __restrict__ in,
                                            const float* __restrict__ gw,
                                            const float* __restrict__ bw,
                                            float* __restrict__ outf,
                                            unsigned short* __restrict__ outb) {
    int row = blockIdx.x, tid = threadIdx.x;
    const float* x = in + (size_t)row * 768;
    float v0 = x[tid], v1 = x[tid + 256], v2 = x[tid + 512];
    float s = v0 + v1 + v2;
    float s2 = v0 * v0 + v1 * v1 + v2 * v2;
#pragma unroll
    for (int off = 32; off; off >>= 1) {
        s += __shfl_down(s, off, 64);
        s2 += __shfl_down(s2, off, 64);
    }
    __shared__ float red[16];
    if ((tid & 63) == 0) { red[tid >> 6] = s; red[8 + (tid >> 6)] = s2; }
    __syncthreads();
    float ssum = red[0] + red[1] + red[2] + red[3];
    float s2sum = red[8] + red[9] + red[10] + red[11];
    float mean = ssum * (1.0f / 768.0f);
    float var = s2sum * (1.0f / 768.0f) - mean * mean;
    float rstd = rsqrtf(var + 1e-5f);
    float* of = outf + (size_t)row * 768;
    unsigned short* ob = outb ? outb + (size_t)row * 768 : nullptr;
    float vv[3] = { v0, v1, v2 };
#pragma unroll
    for (int i = 0; i < 3; i++) {
        int col = tid + i * 256;
        float y = (vv[i] - mean) * rstd * gw[col] + bw[col];
        of[col] = y;
        if constexpr (WB) ob[col] = f2b(y);
    }
}

// ---------------- workspace layout (bytes) ----------------
constexpr size_t OFF_XB    = 0;                          // 8192*768*2
constexpr size_t OFF_QKV   = OFF_XB    + 12582912;       // 8192*2304*2
constexpr size_t OFF_ATT   = OFF_QKV   + 37748736;       // 8192*768*2
constexpr size_t OFF_WQKVT = OFF_ATT   + 12582912;       // 2304*768*2
constexpr size_t OFF_WOT   = OFF_WQKVT + 3538944;        // 768*768*2
constexpr size_t OFF_W1T   = OFF_WOT   + 1179648;        // 3072*768*2
constexpr size_t OFF_W2T   = OFF_W1T   + 4718592;        // 768*3072*2
constexpr size_t OFF_BQKV  = OFF_W2T   + 4718592;        // 2304*4
constexpr size_t OFF_TMP   = OFF_BQKV  + 9216;           // 8192*768*4
constexpr size_t OFF_X1F   = OFF_TMP   + 25165824;       // 8192*768*4
constexpr size_t OFF_X1B   = OFF_X1F   + 25165824;       // 8192*768*2
constexpr size_t OFF_H     = OFF_X1B   + 12582912;       // 8192*3072*2

extern "C" void kernel_launch(void* const* d_in, const int* in_sizes, int n_in,
                              void* d_out, int out_size, void* d_ws, size_t ws_size,
                              hipStream_t stream) {
    const float* x    = (const float*)d_in[0];
    const float* ab   = (const float*)d_in[1];
    const float* Wq   = (const float*)d_in[2];
    const float* bq   = (const float*)d_in[3];
    const float* Wk   = (const float*)d_in[4];
    const float* bk   = (const float*)d_in[5];
    const float* Wv   = (const float*)d_in[6];
    const float* bv   = (const float*)d_in[7];
    const float* Wo   = (const float*)d_in[8];
    const float* bo   = (const float*)d_in[9];
    const float* g1   = (const float*)d_in[10];
    const float* be1  = (const float*)d_in[11];
    const float* W1   = (const float*)d_in[12];
    const float* bf1  = (const float*)d_in[13];
    const float* W2   = (const float*)d_in[14];
    const float* bf2  = (const float*)d_in[15];
    const float* g2   = (const float*)d_in[16];
    const float* be2  = (const float*)d_in[17];

    char* ws = (char*)d_ws;
    unsigned short* xb    = (unsigned short*)(ws + OFF_XB);
    unsigned short* qkv   = (unsigned short*)(ws + OFF_QKV);
    unsigned short* att   = (unsigned short*)(ws + OFF_ATT);
    unsigned short* wqkvt = (unsigned short*)(ws + OFF_WQKVT);
    unsigned short* wot   = (unsigned short*)(ws + OFF_WOT);
    unsigned short* w1t   = (unsigned short*)(ws + OFF_W1T);
    unsigned short* w2t   = (unsigned short*)(ws + OFF_W2T);
    float*          bqkv  = (float*)(ws + OFF_BQKV);
    float*          tmp   = (float*)(ws + OFF_TMP);
    float*          x1f   = (float*)(ws + OFF_X1F);
    unsigned short* x1b   = (unsigned short*)(ws + OFF_X1B);
    unsigned short* hb    = (unsigned short*)(ws + OFF_H);
    float*          out   = (float*)d_out;

    // pre-pass
    k_cvt<<<dim3(MTOT * HDIM / 1024), dim3(256), 0, stream>>>(x, xb, MTOT * HDIM);
    k_wt4<<<dim3(24, 24, 4), dim3(256), 0, stream>>>(Wq, Wk, Wv, Wo, wqkvt);
    k_wt<<<dim3(96, 24), dim3(256), 0, stream>>>(W1, w1t, HDIM, FFDIM);
    k_wt<<<dim3(24, 96), dim3(256), 0, stream>>>(W2, w2t, FFDIM, HDIM);
    k_bias3<<<dim3(9), dim3(256), 0, stream>>>(bq, bk, bv, bqkv);

    // QKV projection: 256x256 tiles
    k_gemm8<8, 0><<<dim3(32, 9), dim3(512), 0, stream>>>(xb, wqkvt, bqkv, nullptr, qkv, nullptr,
                                                         3 * HDIM, HDIM);
    // attention
    k_attn<<<dim3(SEQ / 64, BATCH * NH), dim3(256), 0, stream>>>(qkv, ab, att);
    // output projection + residual (128x128, N=768)
    k_gemm<1><<<dim3(64, 6), dim3(256), 0, stream>>>(att, wot, bo, x, nullptr, tmp,
                                                     HDIM, HDIM);
    k_ln<1><<<dim3(MTOT), dim3(256), 0, stream>>>(tmp, g1, be1, x1f, x1b);
    // FF1 + GELU: 256x256 tiles
    k_gemm8<8, 2><<<dim3(32, 12), dim3(512), 0, stream>>>(x1b, w1t, bf1, nullptr, hb, nullptr,
                                                          FFDIM, HDIM);
    // FF2 + residual: 128x256 tiles (K=3072)
    k_gemm8<4, 1><<<dim3(64, 3), dim3(512), 0, stream>>>(hb, w2t, bf2, x1f, nullptr, tmp,
                                                         HDIM, FFDIM);
    k_ln<0><<<dim3(MTOT), dim3(256), 0, stream>>>(tmp, g2, be2, out, nullptr);
}

// Round 6
// 495.497 us; speedup vs baseline: 1.0791x; 1.0791x over previous
//
#include <hip/hip_runtime.h>
#include <math.h>

#define NH 12
#define HD 64
#define SEQ 1024
#define BATCH 8
#define HDIM 768
#define FFDIM 3072
#define MTOT (BATCH*SEQ)   // 8192

typedef __attribute__((ext_vector_type(8))) short short8;
typedef __attribute__((ext_vector_type(4))) float f32x4;
typedef __attribute__((ext_vector_type(4))) unsigned short ushort4v;

__device__ __forceinline__ unsigned short f2b(float f) {
    union { float f; unsigned u; } v; v.f = f;
    unsigned r = v.u + 0x7fffu + ((v.u >> 16) & 1u);  // RNE
    return (unsigned short)(r >> 16);
}

__device__ __forceinline__ f32x4 mfma16(short8 a, short8 b, f32x4 c) {
    return __builtin_amdgcn_mfma_f32_16x16x32_bf16(a, b, c, 0, 0, 0);
}

// async global->LDS, 16B per lane. HW writes lds_base + lane*16; lds ptr must be wave-uniform.
__device__ __forceinline__ void async_copy16(const unsigned short* g, unsigned short* l) {
    __builtin_amdgcn_global_load_lds(
        (const __attribute__((address_space(1))) unsigned int*)(const void*)g,
        (__attribute__((address_space(3))) unsigned int*)(void*)l, 16, 0, 0);
}

// ---------------- convert f32 -> bf16 ----------------
__global__ __launch_bounds__(256) void k_cvt(const float* __restrict__ in,
                                             unsigned short* __restrict__ out, int n) {
    int idx = (blockIdx.x * 256 + threadIdx.x) * 4;
    if (idx >= n) return;
    float4 v = *reinterpret_cast<const float4*>(in + idx);
    ushort4v o;
    o[0] = f2b(v.x); o[1] = f2b(v.y); o[2] = f2b(v.z); o[3] = f2b(v.w);
    *reinterpret_cast<ushort4v*>(out + idx) = o;
}

// ---------------- transpose + convert: W[K][N] f32 -> WT[N][K] bf16 ----------------
__global__ __launch_bounds__(256) void k_wt4(const float* __restrict__ W0,
                                             const float* __restrict__ W1,
                                             const float* __restrict__ W2,
                                             const float* __restrict__ W3,
                                             unsigned short* __restrict__ WT) {
    __shared__ float t[32][33];
    const float* W = (blockIdx.z == 0) ? W0 : (blockIdx.z == 1) ? W1 :
                     (blockIdx.z == 2) ? W2 : W3;
    unsigned short* dst = WT + (size_t)blockIdx.z * 768 * 768;
    int n0 = blockIdx.x * 32, k0 = blockIdx.y * 32;
    int x = threadIdx.x & 31, y = threadIdx.x >> 5;
#pragma unroll
    for (int i = y; i < 32; i += 8) t[i][x] = W[(size_t)(k0 + i) * 768 + n0 + x];
    __syncthreads();
#pragma unroll
    for (int i = y; i < 32; i += 8) dst[(size_t)(n0 + i) * 768 + k0 + x] = f2b(t[x][i]);
}

__global__ __launch_bounds__(256) void k_wt(const float* __restrict__ W,
                                            unsigned short* __restrict__ WT, int K, int Nn) {
    __shared__ float t[32][33];
    int n0 = blockIdx.x * 32, k0 = blockIdx.y * 32;
    int x = threadIdx.x & 31, y = threadIdx.x >> 5;
#pragma unroll
    for (int i = y; i < 32; i += 8) t[i][x] = W[(size_t)(k0 + i) * Nn + n0 + x];
    __syncthreads();
#pragma unroll
    for (int i = y; i < 32; i += 8) WT[(size_t)(n0 + i) * K + k0 + x] = f2b(t[x][i]);
}

// ---------------- concat qkv bias ----------------
__global__ void k_bias3(const float* __restrict__ a, const float* __restrict__ b,
                        const float* __restrict__ c, float* __restrict__ o) {
    int i = blockIdx.x * 256 + threadIdx.x;
    if (i >= 3 * HDIM) return;
    o[i] = (i < HDIM) ? a[i] : (i < 2 * HDIM ? b[i - HDIM] : c[i - 2 * HDIM]);
}

// ---------------- V pre-transpose: qkv V-cols -> VT[bh][d][n], k-permuted ----------------
// VT[bh][d][kt+slot] = V[b][kt+perm(slot)][h*64+d],  perm(s) = (s&15)*4 + (s>>4).
__global__ __launch_bounds__(256) void k_vtr(const unsigned short* __restrict__ QKV,
                                             unsigned short* __restrict__ VT) {
    __shared__ unsigned short T[64][72];
    int kt = blockIdx.x * 64;
    int bh = blockIdx.y;
    int b = bh / NH, h = bh % NH;
    int tid = threadIdx.x;
#pragma unroll
    for (int it = 0; it < 2; ++it) {
        int idx = tid + it * 256;
        int r = idx >> 3, c8 = (idx & 7) * 8;
        *reinterpret_cast<short8*>(&T[r][c8]) = *reinterpret_cast<const short8*>(
            &QKV[(size_t)(b * SEQ + kt + r) * 2304 + 1536 + h * 64 + c8]);
    }
    __syncthreads();
#pragma unroll
    for (int it = 0; it < 2; ++it) {
        int idx = tid + it * 256;
        int d = idx >> 3, c8 = (idx & 7) * 8;
        short8 o;
#pragma unroll
        for (int j = 0; j < 8; j++) {
            int slot = c8 + j;
            o[j] = (short)T[(slot & 15) * 4 + (slot >> 4)][d];
        }
        *reinterpret_cast<short8*>(&VT[((size_t)bh * 64 + d) * SEQ + kt + c8]) = o;
    }
}

// ---------------- epilogue helper ----------------
template<int EPI>
__device__ __forceinline__ void epi_store(float v, size_t oi,
                                          unsigned short* outb, float* outf,
                                          const float* resid) {
    if constexpr (EPI == 0) {
        outb[oi] = f2b(v);
    } else if constexpr (EPI == 1) {
        outf[oi] = v + resid[oi];
    } else {
        float g = 0.5f * v * (1.0f + erff(v * 0.70710678118654752f));
        outb[oi] = f2b(g);
    }
}

// ---------------- 4-wave 128x128 GEMM (round-4 proven) ----------------
// C[M][N] = A[M][K] * BT[N][K]^T, BK=64, gload_lds into XOR-swizzled LDS.
template<int EPI>
__global__ __launch_bounds__(256) void k_gemm(const unsigned short* __restrict__ A,
                                              const unsigned short* __restrict__ BT,
                                              const float* __restrict__ bias,
                                              const float* __restrict__ resid,
                                              unsigned short* __restrict__ outb,
                                              float* __restrict__ outf,
                                              int Ndim, int Kdim) {
    __shared__ unsigned short As[128 * 64];
    __shared__ unsigned short Bs[128 * 64];
    int tid = threadIdx.x;
    int wid = tid >> 6, lane = tid & 63;
    int wm = wid >> 1, wn = wid & 1;
    int l15 = lane & 15, l16 = lane >> 4;
    int bm = blockIdx.x * 128, bn = blockIdx.y * 128;

    int srow = wid * 8 + (lane >> 3);
    int scol = 8 * ((lane & 7) ^ (lane >> 3));
    const unsigned short* aptr = A + (size_t)(bm + srow) * Kdim + scol;
    const unsigned short* bptr = BT + (size_t)(bn + srow) * Kdim + scol;

    f32x4 acc[4][4] = {};
    const int swz = (l15 & 7) << 3;

    for (int kt = 0; kt < Kdim; kt += 64) {
#pragma unroll
        for (int c = 0; c < 4; c++) {
            async_copy16(aptr + (size_t)c * 32 * Kdim + kt, As + c * 2048 + wid * 512);
            async_copy16(bptr + (size_t)c * 32 * Kdim + kt, Bs + c * 2048 + wid * 512);
        }
        __syncthreads();
#pragma unroll
        for (int kk = 0; kk < 2; kk++) {
            short8 af[4], bfr[4];
            int cidx = (kk * 32 + l16 * 8) ^ swz;
#pragma unroll
            for (int i = 0; i < 4; i++) {
                af[i]  = *reinterpret_cast<const short8*>(&As[(wm * 64 + i * 16 + l15) * 64 + cidx]);
                bfr[i] = *reinterpret_cast<const short8*>(&Bs[(wn * 64 + i * 16 + l15) * 64 + cidx]);
            }
#pragma unroll
            for (int i = 0; i < 4; i++)
#pragma unroll
                for (int j = 0; j < 4; j++)
                    acc[i][j] = mfma16(af[i], bfr[j], acc[i][j]);
        }
        __syncthreads();
    }

#pragma unroll
    for (int i = 0; i < 4; i++)
#pragma unroll
        for (int j = 0; j < 4; j++) {
            int grow0 = bm + wm * 64 + i * 16 + l16 * 4;
            int gcol = bn + wn * 64 + j * 16 + l15;
            float bcol = bias[gcol];
#pragma unroll
            for (int r = 0; r < 4; r++)
                epi_store<EPI>(acc[i][j][r] + bcol, (size_t)(grow0 + r) * Ndim + gcol,
                               outb, outf, resid);
        }
}

// ---------------- flash attention with additive bias ----------------
// K staged with row-perm; V pre-transposed+permuted (VT); bias via float4.
// slot s (tile col label) <-> k = kt + perm(s), perm(s) = (s&15)*4 + (s>>4);
// slot of (c,l15) = c*16+l15  ->  k-col = l15*4 + c.
__global__ __launch_bounds__(256) void k_attn(const unsigned short* __restrict__ QKV,
                                              const unsigned short* __restrict__ VT,
                                              const float* __restrict__ bias,
                                              unsigned short* __restrict__ out) {
    __shared__ unsigned short Ks[64][72];
    __shared__ unsigned short Vt[64][72];   // Vt[d][slot] = V[kt+perm(slot)][d]
    __shared__ unsigned short Ps[4][16][72];

    int bh = blockIdx.y;
    int b = bh / NH, h = bh % NH;
    int q0 = blockIdx.x * 64;
    int tid = threadIdx.x, wid = tid >> 6, lane = tid & 63;
    int l15 = lane & 15, l16 = lane >> 4;

    size_t qrow = (size_t)(b * SEQ + q0 + wid * 16 + l15) * 2304 + h * 64;
    short8 qf0 = *reinterpret_cast<const short8*>(&QKV[qrow + l16 * 8]);
    short8 qf1 = *reinterpret_cast<const short8*>(&QKV[qrow + 32 + l16 * 8]);

    const float* brow = bias + (size_t)h * SEQ * SEQ +
                        (size_t)(q0 + wid * 16 + l16 * 4) * SEQ;

    f32x4 o[4] = {};
    float mrow[4], lrow[4];
#pragma unroll
    for (int r = 0; r < 4; r++) { mrow[r] = -1e30f; lrow[r] = 0.0f; }

    for (int kt = 0; kt < SEQ; kt += 64) {
        // stage K (row-permuted) and VT (linear)
#pragma unroll
        for (int it = 0; it < 2; ++it) {
            int idx = tid + it * 256;           // 0..511
            int r = idx >> 3, c8 = (idx & 7) * 8;
            int pr = (r & 15) * 4 + (r >> 4);   // perm
            *reinterpret_cast<short8*>(&Ks[r][c8]) = *reinterpret_cast<const short8*>(
                &QKV[(size_t)(b * SEQ + kt + pr) * 2304 + 768 + h * 64 + c8]);
            *reinterpret_cast<short8*>(&Vt[r][c8]) = *reinterpret_cast<const short8*>(
                &VT[((size_t)bh * 64 + r) * SEQ + kt + c8]);
        }
        __syncthreads();

        // S = Q K^T  (slot space)
        f32x4 s[4];
#pragma unroll
        for (int c = 0; c < 4; c++) {
            f32x4 t = {};
            t = mfma16(qf0, *reinterpret_cast<const short8*>(&Ks[c * 16 + l15][l16 * 8]), t);
            t = mfma16(qf1, *reinterpret_cast<const short8*>(&Ks[c * 16 + l15][32 + l16 * 8]), t);
            s[c] = t;
        }
        // scale + bias: s[c][r] bias col = kt + l15*4 + c  -> one float4 per row r
#pragma unroll
        for (int r = 0; r < 4; r++) {
            float4 bv = *reinterpret_cast<const float4*>(&brow[(size_t)r * SEQ + kt + l15 * 4]);
            s[0][r] = s[0][r] * 0.125f + bv.x;
            s[1][r] = s[1][r] * 0.125f + bv.y;
            s[2][r] = s[2][r] * 0.125f + bv.z;
            s[3][r] = s[3][r] * 0.125f + bv.w;
        }
        // online softmax (order-independent over slots)
#pragma unroll
        for (int r = 0; r < 4; r++) {
            float mx = fmaxf(fmaxf(s[0][r], s[1][r]), fmaxf(s[2][r], s[3][r]));
#pragma unroll
            for (int off = 1; off < 16; off <<= 1) mx = fmaxf(mx, __shfl_xor(mx, off, 64));
            float mnew = fmaxf(mrow[r], mx);
            float resc = __expf(mrow[r] - mnew);
            mrow[r] = mnew;
            float sum = 0.0f;
#pragma unroll
            for (int c = 0; c < 4; c++) {
                float p = __expf(s[c][r] - mnew);
                s[c][r] = p; sum += p;
            }
#pragma unroll
            for (int off = 1; off < 16; off <<= 1) sum += __shfl_xor(sum, off, 64);
            lrow[r] = lrow[r] * resc + sum;
#pragma unroll
            for (int dc = 0; dc < 4; dc++) o[dc][r] *= resc;
        }
        // P -> LDS (wave-private, slot space)
#pragma unroll
        for (int c = 0; c < 4; c++)
#pragma unroll
            for (int r = 0; r < 4; r++)
                Ps[wid][l16 * 4 + r][c * 16 + l15] = f2b(s[c][r]);
        // PV (Vt rows are d; cols are slots, matching P slots)
#pragma unroll
        for (int dc = 0; dc < 4; dc++) {
            int d = dc * 16 + l15;
#pragma unroll
            for (int kk = 0; kk < 2; kk++) {
                short8 pa = *reinterpret_cast<const short8*>(&Ps[wid][l15][kk * 32 + l16 * 8]);
                short8 vb = *reinterpret_cast<const short8*>(&Vt[d][kk * 32 + l16 * 8]);
                o[dc] = mfma16(pa, vb, o[dc]);
            }
        }
        __syncthreads();
    }

#pragma unroll
    for (int dc = 0; dc < 4; dc++)
#pragma unroll
        for (int r = 0; r < 4; r++) {
            float v = o[dc][r] / lrow[r];
            size_t row = (size_t)(b * SEQ + q0 + wid * 16 + l16 * 4 + r);
            out[row * 768 + h * 64 + dc * 16 + l15] = f2b(v);
        }
}

// ---------------- LayerNorm over 768 cols ----------------
template<int WB>
__global__ __launch_bounds__(256) void k_ln(const float* __restrict__ in,
                                            const float* __restrict__ gw,
                                            const float* __restrict__ bw,
                                            float* __restrict__ outf,
                                            unsigned short* __restrict__ outb) {
    int row = blockIdx.x, tid = threadIdx.x;
    const float* x = in + (size_t)row * 768;
    float v0 = x[tid], v1 = x[tid + 256], v2 = x[tid + 512];
    float s = v0 + v1 + v2;
    float s2 = v0 * v0 + v1 * v1 + v2 * v2;
#pragma unroll
    for (int off = 32; off; off >>= 1) {
        s += __shfl_down(s, off, 64);
        s2 += __shfl_down(s2, off, 64);
    }
    __shared__ float red[16];
    if ((tid & 63) == 0) { red[tid >> 6] = s; red[8 + (tid >> 6)] = s2; }
    __syncthreads();
    float ssum = red[0] + red[1] + red[2] + red[3];
    float s2sum = red[8] + red[9] + red[10] + red[11];
    float mean = ssum * (1.0f / 768.0f);
    float var = s2sum * (1.0f / 768.0f) - mean * mean;
    float rstd = rsqrtf(var + 1e-5f);
    float* of = outf + (size_t)row * 768;
    unsigned short* ob = outb ? outb + (size_t)row * 768 : nullptr;
    float vv[3] = { v0, v1, v2 };
#pragma unroll
    for (int i = 0; i < 3; i++) {
        int col = tid + i * 256;
        float y = (vv[i] - mean) * rstd * gw[col] + bw[col];
        of[col] = y;
        if constexpr (WB) ob[col] = f2b(y);
    }
}

// ---------------- workspace layout (bytes) ----------------
constexpr size_t OFF_XB    = 0;                          // 8192*768*2
constexpr size_t OFF_QKV   = OFF_XB    + 12582912;       // 8192*2304*2
constexpr size_t OFF_ATT   = OFF_QKV   + 37748736;       // 8192*768*2
constexpr size_t OFF_WQKVT = OFF_ATT   + 12582912;       // 2304*768*2
constexpr size_t OFF_WOT   = OFF_WQKVT + 3538944;        // 768*768*2
constexpr size_t OFF_W1T   = OFF_WOT   + 1179648;        // 3072*768*2
constexpr size_t OFF_W2T   = OFF_W1T   + 4718592;        // 768*3072*2
constexpr size_t OFF_BQKV  = OFF_W2T   + 4718592;        // 2304*4
constexpr size_t OFF_TMP   = OFF_BQKV  + 9216;           // 8192*768*4  (also VT during attn)
constexpr size_t OFF_X1F   = OFF_TMP   + 25165824;       // 8192*768*4
constexpr size_t OFF_X1B   = OFF_X1F   + 25165824;       // 8192*768*2
constexpr size_t OFF_H     = OFF_X1B   + 12582912;       // 8192*3072*2

extern "C" void kernel_launch(void* const* d_in, const int* in_sizes, int n_in,
                              void* d_out, int out_size, void* d_ws, size_t ws_size,
                              hipStream_t stream) {
    const float* x    = (const float*)d_in[0];
    const float* ab   = (const float*)d_in[1];
    const float* Wq   = (const float*)d_in[2];
    const float* bq   = (const float*)d_in[3];
    const float* Wk   = (const float*)d_in[4];
    const float* bk   = (const float*)d_in[5];
    const float* Wv   = (const float*)d_in[6];
    const float* bv   = (const float*)d_in[7];
    const float* Wo   = (const float*)d_in[8];
    const float* bo   = (const float*)d_in[9];
    const float* g1   = (const float*)d_in[10];
    const float* be1  = (const float*)d_in[11];
    const float* W1   = (const float*)d_in[12];
    const float* bf1  = (const float*)d_in[13];
    const float* W2   = (const float*)d_in[14];
    const float* bf2  = (const float*)d_in[15];
    const float* g2   = (const float*)d_in[16];
    const float* be2  = (const float*)d_in[17];

    char* ws = (char*)d_ws;
    unsigned short* xb    = (unsigned short*)(ws + OFF_XB);
    unsigned short* qkv   = (unsigned short*)(ws + OFF_QKV);
    unsigned short* att   = (unsigned short*)(ws + OFF_ATT);
    unsigned short* wqkvt = (unsigned short*)(ws + OFF_WQKVT);
    unsigned short* wot   = (unsigned short*)(ws + OFF_WOT);
    unsigned short* w1t   = (unsigned short*)(ws + OFF_W1T);
    unsigned short* w2t   = (unsigned short*)(ws + OFF_W2T);
    float*          bqkv  = (float*)(ws + OFF_BQKV);
    float*          tmp   = (float*)(ws + OFF_TMP);
    unsigned short* vt    = (unsigned short*)(ws + OFF_TMP);   // attn-lifetime only
    float*          x1f   = (float*)(ws + OFF_X1F);
    unsigned short* x1b   = (unsigned short*)(ws + OFF_X1B);
    unsigned short* hb    = (unsigned short*)(ws + OFF_H);
    float*          out   = (float*)d_out;

    // pre-pass
    k_cvt<<<dim3(MTOT * HDIM / 1024), dim3(256), 0, stream>>>(x, xb, MTOT * HDIM);
    k_wt4<<<dim3(24, 24, 4), dim3(256), 0, stream>>>(Wq, Wk, Wv, Wo, wqkvt);
    k_wt<<<dim3(96, 24), dim3(256), 0, stream>>>(W1, w1t, HDIM, FFDIM);
    k_wt<<<dim3(24, 96), dim3(256), 0, stream>>>(W2, w2t, FFDIM, HDIM);
    k_bias3<<<dim3(9), dim3(256), 0, stream>>>(bq, bk, bv, bqkv);

    // QKV projection
    k_gemm<0><<<dim3(64, 18), dim3(256), 0, stream>>>(xb, wqkvt, bqkv, nullptr, qkv, nullptr,
                                                      3 * HDIM, HDIM);
    // V pre-transpose (k-permuted)
    k_vtr<<<dim3(SEQ / 64, BATCH * NH), dim3(256), 0, stream>>>(qkv, vt);
    // attention
    k_attn<<<dim3(SEQ / 64, BATCH * NH), dim3(256), 0, stream>>>(qkv, vt, ab, att);
    // output projection + residual
    k_gemm<1><<<dim3(64, 6), dim3(256), 0, stream>>>(att, wot, bo, x, nullptr, tmp,
                                                     HDIM, HDIM);
    k_ln<1><<<dim3(MTOT), dim3(256), 0, stream>>>(tmp, g1, be1, x1f, x1b);
    // FF1 + GELU
    k_gemm<2><<<dim3(64, 24), dim3(256), 0, stream>>>(x1b, w1t, bf1, nullptr, hb, nullptr,
                                                      FFDIM, HDIM);
    // FF2 + residual
    k_gemm<1><<<dim3(64, 6), dim3(256), 0, stream>>>(hb, w2t, bf2, x1f, nullptr, tmp,
                                                     HDIM, FFDIM);
    k_ln<0><<<dim3(MTOT), dim3(256), 0, stream>>>(tmp, g2, be2, out, nullptr);
}